// Round 2
// baseline (208.561 us; speedup 1.0000x reference)
//
#include <hip/hip_runtime.h>
#include <hip/hip_bf16.h>
#include <math.h>

// out[b, :] = z[b, :] @ W[c_b*12288 : (c_b+1)*12288, :]^T + bias[c_b block]
//   z: (512,128) f32, W: (196608,128) f32, bias: (196608,), out: (512,12288) f32
//   c_b = mod(floor(|np.sum_f32_pairwise(z[b])| * 1000), 16)   (numpy-exact order)
//
// R6 post-mortem of R5: WRITE_SIZE 24.6->42.7MB symmetric with FETCH delta =
// scratch spill round-trip (vf16 64B LDS loads don't lower; allocator gave
// 84 VGPR + scratch). Fix: vf4-only memory ops (every access is exactly one
// ds_read_b128/global_load_dwordx4), arrays only with unrolled const indices.
// Keep z in LDS (broadcast ds_read, lgkmcnt) so W owns vmcnt exclusively;
// deepen W register prefetch 2->4 quads issued as a group per 16-kstep chunk
// (4 loads in flight vs ~900cy HBM latency). zsh [129][48]=24.7KB; n>48
// (P~0.3%/bucket) via 16-slot re-stage + NV=1 second pass.

#define N_LINEARS 16
#define ZD 128
#define BATCH 512
#define BLOCK_OUT 12288
#define STILE 48                  // one W pass for n<=48 (Binom mean 32, sd 5.5)
#define SLOTS 64
#define ZROWS (ZD + 1)
#define TJ 256
#define SS 48                     // zsh row stride (floats)

typedef float vf4 __attribute__((ext_vector_type(4)));

// ws layout: [0,64) counts | [64, 64+32768) lists | [36864, +2048) bp | zgT @65536
#define LISTS_OFF 16
#define BP_OFF (36864 / 4)
#define ZG_OFF_BYTES 65536

// ---------------- Kernel A1: hash (1 block, LDS atomics) ----------------
__global__ __launch_bounds__(512) void hash_kernel(
    const float* __restrict__ z, int* __restrict__ counts,
    int* __restrict__ lists, int* __restrict__ bp) {
  __shared__ int cnt[N_LINEARS];
  const int b = threadIdx.x;
  if (b < N_LINEARS) cnt[b] = 0;
  __syncthreads();

  // numpy pairwise_sum (n=128 <= PW_BLOCKSIZE): 8 stride-8 accumulators,
  // combined ((r0+r1)+(r2+r3))+((r4+r5)+(r6+r7)). float4 loads keep the
  // exact same per-accumulator add order; 32 loads instead of 128.
  const float4* zr4 = (const float4*)(z + b * ZD);
  const float4 pa = zr4[0], pb = zr4[1];
  float r0 = pa.x, r1 = pa.y, r2 = pa.z, r3 = pa.w;
  float r4 = pb.x, r5 = pb.y, r6 = pb.z, r7 = pb.w;
  #pragma unroll
  for (int i = 2; i < ZD / 4; i += 2) {
    const float4 a = zr4[i], d = zr4[i + 1];
    r0 += a.x; r1 += a.y; r2 += a.z; r3 += a.w;
    r4 += d.x; r5 += d.y; r6 += d.z; r7 += d.w;
  }
  float res = ((r0 + r1) + (r2 + r3)) + ((r4 + r5) + (r6 + r7));
  float v = fabsf(res) * 1000.0f;
  int cb = ((int)floorf(v)) & (N_LINEARS - 1);

  int pos = atomicAdd(&cnt[cb], 1);          // LDS atomic: fast, no XCD traffic
  lists[(cb << 9) + pos] = b;
  bp[b] = cb | (pos << 4);

  __syncthreads();
  if (b < N_LINEARS) counts[b] = cnt[b];
}

// ---------------- Kernel A2: z scatter into bucket-grouped k-major zgT ----
// zgT[c][k][slot]; 512 blocks (one per sample) x 128 threads (one per k).
__global__ __launch_bounds__(128) void gather_kernel(
    const float* __restrict__ z, const int* __restrict__ bp,
    float* __restrict__ zgT) {
  const int b = blockIdx.x;
  const int k = threadIdx.x;
  const int v = bp[b];
  const int cb = v & 15;
  const int pos = v >> 4;
  if (pos < SLOTS)
    zgT[(size_t)cb * (ZROWS * SLOTS) + (size_t)k * SLOTS + pos] = z[b * ZD + k];
}

// ---------------- Kernel B: grouped GEMM ----------------
// grid (48 j-tiles, 16 buckets) x 256 thr; thread owns column j, NV*16 sample
// accumulators as vf4 quads. z tile in LDS ([k][48], broadcast ds_read_b128,
// lgkmcnt). W streams through a 4-quad register pipeline (vmcnt exclusively).

template <int NV>
__device__ __forceinline__ void tile_body(
    const float* __restrict__ zs,        // LDS tile base ([k][SS])
    const vf4* __restrict__ Wv, float bj,
    float* __restrict__ out, const int* __restrict__ lst, int m, int j) {
  vf4 acc[NV * 4];
  #pragma unroll
  for (int q = 0; q < NV * 4; ++q) acc[q] = (vf4){bj, bj, bj, bj};

  vf4 wc[4], wn[4];
  #pragma unroll
  for (int i = 0; i < 4; ++i) wc[i] = Wv[i];

  for (int c8 = 0; c8 < 8; ++c8) {       // 8 chunks x 16 ksteps
    const int base = (c8 + 1) * 4;
    #pragma unroll
    for (int i = 0; i < 4; ++i) {        // issue next chunk's 4 quads together
      int wi = base + i;
      wi = wi > 31 ? 31 : wi;            // last chunk: harmless re-reads
      wn[i] = Wv[wi];
    }
    #pragma unroll
    for (int q4 = 0; q4 < 4; ++q4) {
      #pragma unroll
      for (int e = 0; e < 4; ++e) {
        const int k = c8 * 16 + q4 * 4 + e;
        const float wk = wc[q4][e];
        const vf4 wv = {wk, wk, wk, wk};
        #pragma unroll
        for (int q = 0; q < NV * 4; ++q) {
          const vf4 zq = *(const vf4*)&zs[k * SS + q * 4];  // broadcast b128
          acc[q] += zq * wv;             // 2x v_pk_fma_f32
        }
      }
    }
    #pragma unroll
    for (int i = 0; i < 4; ++i) wc[i] = wn[i];
  }

  #pragma unroll
  for (int t = 0; t < NV * 16; ++t)
    if (t < m) out[(size_t)lst[t] * BLOCK_OUT + j] = acc[t >> 2][t & 3];
}

__global__ __launch_bounds__(TJ, 3) void gen_main_kernel(
    const float* __restrict__ W, const float* __restrict__ bias,
    float* __restrict__ out, const int* __restrict__ counts,
    const int* __restrict__ lists, const float* __restrict__ zgT) {
  __shared__ float zsh[ZROWS * SS];      // 24,768 B: z tile [k][48] + pad row
  __shared__ int   lsh[SLOTS];
  const int c = blockIdx.y;
  const int j = blockIdx.x * TJ + threadIdx.x;
  int n = counts[c];
  n = n > SLOTS ? SLOTS : n;
  if (n == 0) return;                    // uniform per block: safe before barrier

  const float* __restrict__ zg = zgT + (size_t)c * (ZROWS * SLOTS);
  {  // stage slots [0,48) of 128 k-rows: 1536 quads == 6*256, no guard
    #pragma unroll
    for (int i = 0; i < 6; ++i) {
      const int idx = threadIdx.x + i * TJ;
      const int k = idx / 12, q = idx % 12;
      *(vf4*)&zsh[k * SS + q * 4] = *(const vf4*)&zg[k * SLOTS + q * 4];
    }
    if (threadIdx.x < SLOTS) lsh[threadIdx.x] = lists[(c << 9) + threadIdx.x];
  }
  __syncthreads();

  const size_t row = (size_t)c * BLOCK_OUT + (size_t)j;
  const vf4* __restrict__ Wv = (const vf4*)(W + row * (size_t)ZD);
  const float bj = bias[row];

  const int m1 = n > STILE ? STILE : n;
  if (m1 <= 16)                          // uniform branch (n same across block)
    tile_body<1>(zsh, Wv, bj, out, lsh, m1, j);
  else if (m1 <= 32)
    tile_body<2>(zsh, Wv, bj, out, lsh, m1, j);
  else
    tile_body<3>(zsh, Wv, bj, out, lsh, m1, j);

  if (n > STILE) {                       // rare (P ~ 0.3%/bucket): re-stage 16 slots
    __syncthreads();                     // all zsh reads of pass 1 done
    #pragma unroll
    for (int i = 0; i < 2; ++i) {        // 512 quads == 2*256
      const int idx = threadIdx.x + i * TJ;
      const int k = idx >> 2, q = idx & 3;
      *(vf4*)&zsh[k * SS + q * 4] = *(const vf4*)&zg[k * SLOTS + STILE + q * 4];
    }
    __syncthreads();
    tile_body<1>(zsh, Wv, bj, out, lsh + STILE, n - STILE, j);
  }
}

extern "C" void kernel_launch(void* const* d_in, const int* in_sizes, int n_in,
                              void* d_out, int out_size, void* d_ws, size_t ws_size,
                              hipStream_t stream) {
  const float* z    = (const float*)d_in[0];   // 512*128
  const float* W    = (const float*)d_in[1];   // 196608*128
  const float* bias = (const float*)d_in[2];   // 196608
  float* out = (float*)d_out;                  // 512*12288

  int*   counts = (int*)d_ws;
  int*   lists  = (int*)d_ws + LISTS_OFF;
  int*   bp     = (int*)d_ws + BP_OFF;
  float* zgT    = (float*)((char*)d_ws + ZG_OFF_BYTES); // 16*129*64 floats

  hipLaunchKernelGGL(hash_kernel, dim3(1), dim3(BATCH), 0, stream,
                     z, counts, lists, bp);
  hipLaunchKernelGGL(gather_kernel, dim3(BATCH), dim3(ZD), 0, stream,
                     z, bp, zgT);

  dim3 grid(BLOCK_OUT / TJ, N_LINEARS);        // (48, 16)
  hipLaunchKernelGGL(gen_main_kernel, grid, dim3(TJ), 0, stream,
                     W, bias, out, counts, lists, zgT);
}

// Round 3
// 188.844 us; speedup vs baseline: 1.1044x; 1.1044x over previous
//
#include <hip/hip_runtime.h>
#include <hip/hip_bf16.h>
#include <math.h>

// out[b, :] = z[b, :] @ W[c_b*12288 : (c_b+1)*12288, :]^T + bias[c_b block]
//   z: (512,128) f32, W: (196608,128) f32, bias: (196608,), out: (512,12288) f32
//   c_b = mod(floor(|np.sum_f32_pairwise(z[b])| * 1000), 16)   (numpy-exact order)
//
// R7: R5/R6 regressions were scratch spills caused by passing the __shared__
// z tile through a generic pointer argument (flat loads -> scheduler hoists
// like 500cy globals -> live-range explosion -> 55MB spill round-trip, and
// flat ticks BOTH counters so no decoupling). This version is R0's exact
// verified structure (vf16 accs in unified AGPRs, VGPR=40) with exactly two
// changes: (1) z tile staged once to LDS and read via DIRECT zsh[] indexing
// in kernel scope (lowers to ds_read_b128 broadcast, lgkmcnt) so W owns
// vmcnt exclusively (in-order vmcnt no longer couples z waits to the W
// stream); (2) W register ring deepened 2->4 quads (prefetch distance 3
// kc-iters ~ 1700cy across 3 waves/SIMD > 900cy HBM latency).

#define N_LINEARS 16
#define ZD 128
#define BATCH 512
#define BLOCK_OUT 12288
#define STILE 48                  // one W pass for n<=48 (Binom mean 32, sd 5.5)
#define SLOTS 64
#define ZROWS (ZD + 1)
#define TJ 256

typedef float vf16 __attribute__((ext_vector_type(16)));
typedef vf16 vf16u __attribute__((aligned(16)));   // 16B-aligned vector loads

// ws layout: [0,64) counts | [64, 64+32768) lists | [36864, +2048) bp | zgT @65536
#define LISTS_OFF 16
#define BP_OFF (36864 / 4)
#define ZG_OFF_BYTES 65536

// ---------------- Kernel A1: hash (1 block, LDS atomics) ----------------
__global__ __launch_bounds__(512) void hash_kernel(
    const float* __restrict__ z, int* __restrict__ counts,
    int* __restrict__ lists, int* __restrict__ bp) {
  __shared__ int cnt[N_LINEARS];
  const int b = threadIdx.x;
  if (b < N_LINEARS) cnt[b] = 0;
  __syncthreads();

  // numpy pairwise_sum (n=128 <= PW_BLOCKSIZE): 8 stride-8 accumulators,
  // combined ((r0+r1)+(r2+r3))+((r4+r5)+(r6+r7)). float4 loads keep the
  // exact same per-accumulator add order; 32 loads instead of 128.
  const float4* zr4 = (const float4*)(z + b * ZD);
  const float4 pa = zr4[0], pb = zr4[1];
  float r0 = pa.x, r1 = pa.y, r2 = pa.z, r3 = pa.w;
  float r4 = pb.x, r5 = pb.y, r6 = pb.z, r7 = pb.w;
  #pragma unroll
  for (int i = 2; i < ZD / 4; i += 2) {
    const float4 a = zr4[i], d = zr4[i + 1];
    r0 += a.x; r1 += a.y; r2 += a.z; r3 += a.w;
    r4 += d.x; r5 += d.y; r6 += d.z; r7 += d.w;
  }
  float res = ((r0 + r1) + (r2 + r3)) + ((r4 + r5) + (r6 + r7));
  float v = fabsf(res) * 1000.0f;
  int cb = ((int)floorf(v)) & (N_LINEARS - 1);

  int pos = atomicAdd(&cnt[cb], 1);          // LDS atomic: fast, no XCD traffic
  lists[(cb << 9) + pos] = b;
  bp[b] = cb | (pos << 4);

  __syncthreads();
  if (b < N_LINEARS) counts[b] = cnt[b];
}

// ---------------- Kernel A2: z scatter into bucket-grouped k-major zgT ----
// zgT[c][k][slot]; 512 blocks (one per sample) x 128 threads (one per k).
__global__ __launch_bounds__(128) void gather_kernel(
    const float* __restrict__ z, const int* __restrict__ bp,
    float* __restrict__ zgT) {
  const int b = blockIdx.x;
  const int k = threadIdx.x;
  const int v = bp[b];
  const int cb = v & 15;
  const int pos = v >> 4;
  if (pos < SLOTS)
    zgT[(size_t)cb * (ZROWS * SLOTS) + (size_t)k * SLOTS + pos] = z[b * ZD + k];
}

// ---------------- Kernel B: grouped GEMM ----------------
// grid (48 j-tiles, 16 buckets) x 256 thr; thread owns column j, 48 sample
// accumulators in 3x vf16 (unified-AGPR-friendly, proven R0 shape). z tile
// in LDS, read by DIRECT zsh[] indexing (ds_read_b128 broadcast, lgkmcnt).
// W streams through a 4-deep register ring (sole vmcnt user, never drained).

// ZLOAD reads the __shared__ array `zsh` directly (macro expands in kernel
// scope) -> guaranteed ds_read lowering, no generic-pointer flat loads.
#define ZLOAD(N0, N1, N2, K1)                                        \
  { const int zo_ = (K1) * SLOTS + s0;                               \
    N0 = *(const vf16u*)&zsh[zo_];                                   \
    N1 = *(const vf16u*)&zsh[zo_ + 16];                              \
    N2 = *(const vf16u*)&zsh[zo_ + 32]; }

#define ZFMA(C0, C1, C2, WK)                                         \
  { const float wk_ = (WK);                                          \
    vf16 wv_;                                                        \
    _Pragma("unroll") for (int e = 0; e < 16; ++e) wv_[e] = wk_;     \
    acc0 += C0 * wv_; acc1 += C1 * wv_; acc2 += C2 * wv_; }

#define STEP(C0, C1, C2, N0, N1, N2, K1, WK)                         \
  ZLOAD(N0, N1, N2, K1) ZFMA(C0, C1, C2, WK)

__global__ __launch_bounds__(TJ, 3) void gen_main_kernel(
    const float* __restrict__ W, const float* __restrict__ bias,
    float* __restrict__ out, const int* __restrict__ counts,
    const int* __restrict__ lists, const float* __restrict__ zgT) {
  // 128 rows x 64 slots, +32 floats of slack so pass-2 (s0=48) reads of
  // slots 48..95 stay in-bounds (values are garbage, masked by t<m).
  __shared__ float zsh[ZD * SLOTS + 32 + 64];
  const int c = blockIdx.y;
  const int j = blockIdx.x * TJ + threadIdx.x;
  int n = counts[c];
  n = n > SLOTS ? SLOTS : n;
  if (n == 0) return;                    // uniform per block: safe before barrier

  {  // stage rows 0..127 (8192 floats = 2048 quads = 8*256, linear, coalesced)
    const float4* zg4 = (const float4*)(zgT + (size_t)c * (ZROWS * SLOTS));
    float4* ls4 = (float4*)zsh;
    #pragma unroll
    for (int i = 0; i < 8; ++i) {
      const int idx = threadIdx.x + i * TJ;
      ls4[idx] = zg4[idx];
    }
  }
  __syncthreads();

  const size_t row = (size_t)c * BLOCK_OUT + (size_t)j;
  const float4* __restrict__ Wv = (const float4*)(W + row * (size_t)ZD);
  const float bj = bias[row];
  const int* __restrict__ lst = lists + (c << 9);

  for (int s0 = 0; s0 < n; s0 += STILE) {
    const int m = n - s0;
    vf16 acc0, acc1, acc2;
    #pragma unroll
    for (int e = 0; e < 16; ++e) { acc0[e] = bj; acc1[e] = bj; acc2[e] = bj; }

    vf16 zA0, zA1, zA2, zB0, zB1, zB2;
    ZLOAD(zA0, zA1, zA2, 0)
    float4 w0 = Wv[0];
    float4 w1 = Wv[1];
    float4 w2 = Wv[2];
    float4 w3 = Wv[3];

    #pragma unroll 4
    for (int kc = 0; kc < ZD / 4; ++kc) {
      const int k0 = kc * 4;
      STEP(zA0, zA1, zA2, zB0, zB1, zB2, k0 + 1, w0.x)
      STEP(zB0, zB1, zB2, zA0, zA1, zA2, k0 + 2, w0.y)
      STEP(zA0, zA1, zA2, zB0, zB1, zB2, k0 + 3, w0.z)
      STEP(zB0, zB1, zB2, zA0, zA1, zA2, k0 + 4, w0.w)  // kc=31: row 128 slack, unused
      w0 = w1; w1 = w2; w2 = w3;
      const int wi = kc + 4 > 31 ? 31 : kc + 4;
      w3 = Wv[wi];                       // ring depth 4: auto-wait is vmcnt(3)
    }

    #pragma unroll
    for (int t = 0; t < 16; ++t)
      if (t < m) out[(size_t)lst[s0 + t] * BLOCK_OUT + j] = acc0[t];
    #pragma unroll
    for (int t = 0; t < 16; ++t)
      if (16 + t < m) out[(size_t)lst[s0 + 16 + t] * BLOCK_OUT + j] = acc1[t];
    #pragma unroll
    for (int t = 0; t < 16; ++t)
      if (32 + t < m) out[(size_t)lst[s0 + 32 + t] * BLOCK_OUT + j] = acc2[t];
  }
}

extern "C" void kernel_launch(void* const* d_in, const int* in_sizes, int n_in,
                              void* d_out, int out_size, void* d_ws, size_t ws_size,
                              hipStream_t stream) {
  const float* z    = (const float*)d_in[0];   // 512*128
  const float* W    = (const float*)d_in[1];   // 196608*128
  const float* bias = (const float*)d_in[2];   // 196608
  float* out = (float*)d_out;                  // 512*12288

  int*   counts = (int*)d_ws;
  int*   lists  = (int*)d_ws + LISTS_OFF;
  int*   bp     = (int*)d_ws + BP_OFF;
  float* zgT    = (float*)((char*)d_ws + ZG_OFF_BYTES); // 16*129*64 floats

  hipLaunchKernelGGL(hash_kernel, dim3(1), dim3(BATCH), 0, stream,
                     z, counts, lists, bp);
  hipLaunchKernelGGL(gather_kernel, dim3(BATCH), dim3(ZD), 0, stream,
                     z, bp, zgT);

  dim3 grid(BLOCK_OUT / TJ, N_LINEARS);        // (48, 16)
  hipLaunchKernelGGL(gen_main_kernel, grid, dim3(TJ), 0, stream,
                     W, bias, out, counts, lists, zgT);
}